// Round 1
// baseline (265.567 us; speedup 1.0000x reference)
//
#include <hip/hip_runtime.h>
#include <hip/hip_fp16.h>

// GCN1: ChebConv(K=3) -> global max pool -> MLP(32->1024->512->4)
// fp32 floats, int32 indices (established rounds 0-3).
// Round 19: (a) k_bscatter occupancy fix: 1024-thread blocks x HB=512
// (16 waves/block, 2 blocks/CU -> latency hiding; was 6.6% occupancy);
// (b) kill the entire row/rbuck path: out-degree now via one global
// atomicAdd per edge (1.6M atomics over 100K addrs, ~16/addr at L2) --
// removes 3.2M LDS atomics, the uncoalesced rbuck byte scatter, and
// k_prep's 1.6M uint8 gathers.

#define NT 256
#define NTS 1024    // bscatter block size
#define BSHIFT 8
#define BSIZE 256   // nodes per bucket; NBK = ceil(N/256) = 391 <= 512
#define HB 512      // blocks for the scatter pass
#define CAP 5120    // bucket capacity (expected 4096, 16-sigma pad)

typedef _Float16 half8 __attribute__((ext_vector_type(8)));
typedef float f32x4 __attribute__((ext_vector_type(4)));

__device__ __forceinline__ void atomicMaxFloat(float* addr, float val) {
    if (val >= 0.0f) atomicMax((int*)addr, __float_as_int(val));
    else             atomicMin((unsigned int*)addr, __float_as_uint(val));
}

#define ACC8(raw)                                        \
    do {                                                 \
        const __half2* hp_ = (const __half2*)&(raw);     \
        float2 f0_ = __half22float2(hp_[0]);             \
        float2 f1_ = __half22float2(hp_[1]);             \
        float2 f2_ = __half22float2(hp_[2]);             \
        float2 f3_ = __half22float2(hp_[3]);             \
        a0 += f0_.x; a1 += f0_.y; a2 += f1_.x; a3 += f1_.y; \
        a4 += f2_.x; a5 += f2_.y; a6 += f3_.x; a7 += f3_.y; \
    } while (0)

// ---- init: g=-inf, wfrag precompute, bucket cursors ----
__global__ __launch_bounds__(512) void k_init(float* __restrict__ g,
                                              const float* __restrict__ Wc,
                                              _Float16* __restrict__ wfrag,
                                              int* __restrict__ bcur, int NBK) {
    int tid = threadIdx.x;
    for (int i = tid; i < 64 * 32; i += 512) g[i] = -__builtin_inff();
    if (tid < 384) {
        int combo = tid >> 6, lane = tid & 63;
        int mat = combo >> 1, n = combo & 1;
        int m = lane & 15, quad = lane >> 4;
        #pragma unroll
        for (int j = 0; j < 8; j++)
            wfrag[(size_t)combo * 512 + lane * 8 + j] =
                (_Float16)Wc[mat * 1024 + (quad * 8 + j) * 32 + n * 16 + m];
    }
    if (tid < NBK) bcur[tid] = tid * CAP;
}

// ---- self-counting scatter: col->ebuck packed int; deg via global atomics ----
__global__ __launch_bounds__(NTS) void k_bscatter(const int* __restrict__ row,
                                                  const int* __restrict__ col,
                                                  int* __restrict__ bcur,
                                                  int* __restrict__ degcnt,
                                                  int* __restrict__ ebuck,
                                                  int E, int NBK, int epb) {
    __shared__ int lhc[512], lbasec[512];
    int tid = threadIdx.x;
    for (int i = tid; i < NBK; i += NTS) lhc[i] = 0;
    __syncthreads();
    int start = blockIdx.x * epb;
    int end = min(start + epb, E);
    // pass A: count this segment's col-bucket histogram (segment stays L1-hot)
    for (int e = start + tid; e < end; e += NTS)
        atomicAdd(&lhc[col[e] >> BSHIFT], 1);  // LDS
    __syncthreads();
    for (int i = tid; i < NBK; i += NTS) {
        int vc = lhc[i];
        lbasec[i] = vc ? atomicAdd(&bcur[i], vc) : 0;
        lhc[i] = 0;
    }
    __syncthreads();
    // pass B: scatter + out-degree count
    for (int e = start + tid; e < end; e += NTS) {
        int r = row[e], c = col[e];
        atomicAdd(&degcnt[r], 1);  // global, fire-and-forget (L2)
        int bc_ = c >> BSHIFT;
        int li = atomicAdd(&lhc[bc_], 1);  // LDS
        ebuck[lbasec[bc_] + li] = (r << BSHIFT) | (c & (BSIZE - 1));  // r<2^17: fits
    }
}

// ---- fused prep: deg -> dis/rdis; x->xh/xsh; 1024-bin sort of ebuck ----
// bin = (cl<<2) | (src>>15): each node's entry list is src-range-major,
// ranges of 32768 nodes (1.6MB fp16 rows -> per-XCD L2 resident).
__global__ __launch_bounds__(NT) void k_prep(
    const int* __restrict__ degcnt,
    const int* __restrict__ bcur, const int* __restrict__ ebuck,
    const float* __restrict__ x,
    float* __restrict__ dis, float* __restrict__ rdis,
    __half* __restrict__ xh, __half* __restrict__ xsh,
    int* __restrict__ offs, int* __restrict__ entries, int N) {
    __shared__ int cnt[1024];
    __shared__ int tsum[256];
    __shared__ float sdis[256];
    int b = blockIdx.x, tid = threadIdx.x;
    int ebase = b * CAP, eend = bcur[b];
    cnt[tid] = 0; cnt[tid + 256] = 0; cnt[tid + 512] = 0; cnt[tid + 768] = 0;
    int node = (b << BSHIFT) + tid;
    int dcount = (node < N) ? degcnt[node] : 0;
    float d = (dcount > 0) ? rsqrtf((float)dcount) : 0.0f;
    if (node < N) {
        dis[node] = d;
        rdis[node] = (dcount > 0) ? sqrtf((float)dcount) : 0.0f;
    }
    sdis[tid] = d;
    __syncthreads();
    // count 1024 bins
    for (int e = ebase + tid; e < eend; e += NT) {
        int pv = ebuck[e];
        atomicAdd(&cnt[((pv & (BSIZE - 1)) << 2) | ((pv >> BSHIFT) >> 15)], 1);
    }
    __syncthreads();
    // per-node (4-bin) sums + 256-wide scan
    int s0 = cnt[tid * 4], s1 = cnt[tid * 4 + 1], s2 = cnt[tid * 4 + 2], s3 = cnt[tid * 4 + 3];
    int tot = s0 + s1 + s2 + s3;
    tsum[tid] = tot;
    __syncthreads();
    for (int off = 1; off < 256; off <<= 1) {
        int t = (tid >= off) ? tsum[tid - off] : 0;
        __syncthreads();
        tsum[tid] += t;
        __syncthreads();
    }
    int excl = tsum[tid] - tot;
    if (node < N) offs[node] = ((ebase + excl) << 9) | tot;  // base < 2^21, tot < 512
    cnt[tid * 4]     = ebase + excl;
    cnt[tid * 4 + 1] = ebase + excl + s0;
    cnt[tid * 4 + 2] = ebase + excl + s0 + s1;
    cnt[tid * 4 + 3] = ebase + excl + s0 + s1 + s2;
    __syncthreads();
    // scatter (absolute positions in cursors)
    for (int e = ebase + tid; e < eend; e += NT) {
        int pv = ebuck[e];
        int src = pv >> BSHIFT;
        int li = atomicAdd(&cnt[((pv & (BSIZE - 1)) << 2) | (src >> 15)], 1);  // LDS
        entries[li] = src;
    }
    // x -> xh (fp16) and xsh (dis-scaled fp16)
    int nodebase = b << BSHIFT;
    for (int i4 = tid; i4 < 2048; i4 += NT) {  // 256 nodes x 8 float4
        int gnode = nodebase + (i4 >> 3);
        if (gnode >= N) break;
        float4 v = ((const float4*)x)[(size_t)nodebase * 8 + i4];
        float dd = sdis[i4 >> 3];
        float2 o, os;
        ((__half2*)&o)[0] = __floats2half2_rn(v.x, v.y);
        ((__half2*)&o)[1] = __floats2half2_rn(v.z, v.w);
        ((__half2*)&os)[0] = __floats2half2_rn(dd * v.x, dd * v.y);
        ((__half2*)&os)[1] = __floats2half2_rn(dd * v.z, dd * v.w);
        ((float2*)xh)[(size_t)nodebase * 8 + i4] = o;
        ((float2*)xsh)[(size_t)nodebase * 8 + i4] = os;
    }
}

// ---- prop1: xs2 = -dis^2 * sum xs[r] (fp16). 8 thr/node: 2 edge-halves x 4 q. ----
__global__ __launch_bounds__(NT) void k_prop1(const int* __restrict__ offs,
                                              const int* __restrict__ entries,
                                              const float* __restrict__ dis,
                                              const __half* __restrict__ xsh,
                                              __half* __restrict__ xs2h, int N) {
    int idx = blockIdx.x * blockDim.x + threadIdx.x;
    int node = idx >> 3, sp = (idx >> 2) & 1, q = idx & 3;
    if (node >= N) return;
    int pv = offs[node];
    int s = pv >> 9, deg = pv & 511;
    int mid = s + (deg >> 1), t = s + deg;
    int lo = sp ? mid : s;
    int hi = sp ? t : mid;
    float a0 = 0, a1 = 0, a2 = 0, a3 = 0, a4 = 0, a5 = 0, a6 = 0, a7 = 0;
    for (int e = lo; e < hi; e++) {
        int r = entries[e];
        float4 w = *(const float4*)(xsh + (size_t)r * 32 + q * 8);
        ACC8(w);
    }
    a0 += __shfl_xor(a0, 4); a1 += __shfl_xor(a1, 4);
    a2 += __shfl_xor(a2, 4); a3 += __shfl_xor(a3, 4);
    a4 += __shfl_xor(a4, 4); a5 += __shfl_xor(a5, 4);
    a6 += __shfl_xor(a6, 4); a7 += __shfl_xor(a7, 4);
    if (sp == 0) {
        float d = dis[node];
        float sd = -d * d;  // xs2 = dis * tx1 = -dis^2 * S
        float4 ov;
        ((__half2*)&ov)[0] = __floats2half2_rn(sd * a0, sd * a1);
        ((__half2*)&ov)[1] = __floats2half2_rn(sd * a2, sd * a3);
        ((__half2*)&ov)[2] = __floats2half2_rn(sd * a4, sd * a5);
        ((__half2*)&ov)[3] = __floats2half2_rn(sd * a6, sd * a7);
        *(float4*)(xs2h + (size_t)node * 32 + q * 8) = ov;
    }
}

// ---- fused prop2 + MFMA combine + segmented max ----
// T1 reconstructed as xs2 * rdis (rdis = sqrt(deg) = 1/dis; 0 if deg=0).
__global__ __launch_bounds__(NT) void k_combine_f(
    const int* __restrict__ offs, const int* __restrict__ entries,
    const float* __restrict__ dis, const float* __restrict__ rdis,
    const __half* __restrict__ xs2h, const _Float16* __restrict__ xh,
    const _Float16* __restrict__ wfrag, const float* __restrict__ bc,
    const int* __restrict__ batch, float* __restrict__ g, int N) {
    __shared__ float sb[32];
    __shared__ float sp2[64][33];
    __shared__ float hs[64][33];
    __shared__ int sbatch[64];

    int tid = threadIdx.x;
    if (tid < 32) sb[tid] = bc[tid];
    int rowbase = blockIdx.x * 64;
    if (tid >= 64 && tid < 128) {
        int gr = rowbase + tid - 64;
        sbatch[tid - 64] = (gr < N) ? batch[gr] : -1;
    }

    // phase 1: gather prop2 into sp2 (4 thr/node)
    int node_l = tid >> 2, q = tid & 3;
    int gnode = rowbase + node_l;
    if (gnode < N) {
        int pv = offs[gnode];
        int s = pv >> 9, t = s + (pv & 511);
        float a0 = 0, a1 = 0, a2 = 0, a3 = 0, a4 = 0, a5 = 0, a6 = 0, a7 = 0;
        for (int e = s; e < t; e++) {
            int r = entries[e];
            float4 w = *(const float4*)(xs2h + (size_t)r * 32 + q * 8);
            ACC8(w);
        }
        float sc = -dis[gnode];
        float* p = &sp2[node_l][q * 8];
        p[0] = sc * a0; p[1] = sc * a1; p[2] = sc * a2; p[3] = sc * a3;
        p[4] = sc * a4; p[5] = sc * a5; p[6] = sc * a6; p[7] = sc * a7;
    }
    __syncthreads();

    // phase 2: MFMA with precomputed B-fragments
    int wave = tid >> 6;
    int lane = tid & 63;
    int m = lane & 15;
    int quad = lane >> 4;
    int grow = rowbase + wave * 16 + m;

    half8 a0 = {}, a1 = {}, a2 = {};
    if (grow < N) {
        size_t off = (size_t)grow * 32 + quad * 8;
        a0 = *(const half8*)(xh + off);
        half8 x2 = *(const half8*)((const _Float16*)xs2h + off);
        float rd = rdis[grow];
        const float* p = &sp2[wave * 16 + m][quad * 8];
        #pragma unroll
        for (int j = 0; j < 8; j++) {
            a1[j] = (_Float16)((float)x2[j] * rd);          // T1 = xs2 / dis
            a2[j] = (_Float16)(2.0f * p[j] - (float)a0[j]); // T2 = 2*P2 - T0
        }
    }

    const half8* wf = (const half8*)wfrag;
    f32x4 acc[2];
    #pragma unroll
    for (int n = 0; n < 2; n++) {
        f32x4 c = {0.f, 0.f, 0.f, 0.f};
        c = __builtin_amdgcn_mfma_f32_16x16x32_f16(a0, wf[(0 * 2 + n) * 64 + lane], c, 0, 0, 0);
        c = __builtin_amdgcn_mfma_f32_16x16x32_f16(a1, wf[(1 * 2 + n) * 64 + lane], c, 0, 0, 0);
        c = __builtin_amdgcn_mfma_f32_16x16x32_f16(a2, wf[(2 * 2 + n) * 64 + lane], c, 0, 0, 0);
        acc[n] = c;
    }

    #pragma unroll
    for (int n = 0; n < 2; n++)
        #pragma unroll
        for (int r = 0; r < 4; r++)
            hs[wave * 16 + quad * 4 + r][n * 16 + m] = acc[n][r] + sb[n * 16 + m];
    __syncthreads();

    // phase 3: segmented max
    int f = tid & 31, s = tid >> 5;
    int curb = -1;
    float curm = 0.0f;
    for (int j = s * 8; j < s * 8 + 8; j++) {
        int b = sbatch[j];
        if (b < 0) continue;
        float v = hs[j][f];
        if (b != curb) {
            if (curb >= 0) atomicMaxFloat(&g[curb * 32 + f], curm);
            curb = b;
            curm = v;
        } else {
            curm = fmaxf(curm, v);
        }
    }
    if (curb >= 0) atomicMaxFloat(&g[curb * 32 + f], curm);
}

// ---- fused MLP1+MLP2: block (gi,ks) computes h1 chunk in LDS then W2 chunk ----
__global__ __launch_bounds__(NT) void k_mlp12(const float* __restrict__ g,
                                              const float* __restrict__ W1,
                                              const float* __restrict__ b1,
                                              const float* __restrict__ W2,
                                              float* __restrict__ h2acc) {
    __shared__ float sg[32];
    __shared__ float sh[128];
    int gi = blockIdx.x >> 3, ks = blockIdx.x & 7;
    int tid = threadIdx.x;
    if (tid < 32) sg[tid] = g[gi * 32 + tid];
    __syncthreads();
    if (tid < 128) {
        int c = ks * 128 + tid;
        float a = b1[c];
        #pragma unroll
        for (int k = 0; k < 32; k++) a += sg[k] * W1[k * 1024 + c];
        sh[tid] = fmaxf(a, 0.0f);
    }
    __syncthreads();
    const float* w = W2 + (size_t)(ks * 128) * 512;
    float acc0 = 0.0f, acc1 = 0.0f;
    for (int k = 0; k < 128; k++) {
        float h = sh[k];
        acc0 += h * w[k * 512 + tid];
        acc1 += h * w[k * 512 + tid + 256];
    }
    atomicAdd(&h2acc[gi * 512 + tid], acc0);
    atomicAdd(&h2acc[gi * 512 + tid + 256], acc1);
}

// ---- MLP layer 3 (parallel): out[64,4] = relu(h2acc + b2) @ W3 + b3 ----
__global__ __launch_bounds__(NT) void k_mlp3p(const float* __restrict__ h2acc,
                                              const float* __restrict__ b2,
                                              const float* __restrict__ W3,
                                              const float* __restrict__ b3,
                                              float* __restrict__ out) {
    __shared__ float sp[256];
    int gi = blockIdx.x;
    int tid = threadIdx.x;
    int j = tid & 3, slot = tid >> 2;  // 64 K-slots x 4 outputs
    float part = 0.0f;
    #pragma unroll
    for (int kk = 0; kk < 8; kk++) {
        int k = slot * 8 + kk;
        float h = fmaxf(h2acc[gi * 512 + k] + b2[k], 0.0f);
        part += h * W3[k * 4 + j];
    }
    sp[tid] = part;
    __syncthreads();
    for (int s = 32; s >= 1; s >>= 1) {
        if (slot < s) sp[tid] += sp[(slot + s) * 4 + j];
        __syncthreads();
    }
    if (slot == 0) out[gi * 4 + j] = sp[j] + b3[j];
}

extern "C" void kernel_launch(void* const* d_in, const int* in_sizes, int n_in,
                              void* d_out, int out_size, void* d_ws, size_t ws_size,
                              hipStream_t stream) {
    const float* x   = (const float*)d_in[0];
    const int* ei    = (const int*)d_in[1];
    const int* batch = (const int*)d_in[2];
    const float* Wc  = (const float*)d_in[3];
    const float* bc  = (const float*)d_in[4];
    const float* W1  = (const float*)d_in[5];
    const float* b1  = (const float*)d_in[6];
    const float* W2  = (const float*)d_in[7];
    const float* b2  = (const float*)d_in[8];
    const float* W3  = (const float*)d_in[9];
    const float* b3  = (const float*)d_in[10];
    float* out       = (float*)d_out;

    const int N = in_sizes[2];      // 100000
    const int E = in_sizes[1] / 2;  // 1.6M
    const int* row = ei;
    const int* col = ei + E;
    const int NBK = (N + BSIZE - 1) / BSIZE;   // 391 (<= 512)
    const int epb = (E + HB - 1) / HB;
    const size_t PADE = (size_t)NBK * CAP;     // padded edge capacity

    // workspace layout
    float* h2acc    = (float*)d_ws;                  // 64*512 (memset)
    int* degcnt     = (int*)(h2acc + 64 * 512);      // N (memset, contiguous)
    int* bcur       = degcnt + N;                    // 512
    float* dis      = (float*)(bcur + 512);          // N
    float* rdis     = dis + N;                       // N
    int* offs       = (int*)(rdis + N);              // N (+4 pad)
    int* ebuck      = offs + N + 4;                  // PADE ints
    int* entries    = ebuck + PADE;                  // PADE ints
    _Float16* xh    = (_Float16*)(entries + PADE);   // 32N halfs
    _Float16* xsh   = xh + (size_t)N * 32;           // 32N halfs
    _Float16* xs2h  = xsh + (size_t)N * 32;          // 32N halfs
    float* g        = (float*)(xs2h + (size_t)N * 32);  // 64*32
    _Float16* wfrag = (_Float16*)(g + 64 * 32);      // 6*512 halfs

    // zero h2acc + degcnt in one contiguous fill
    hipMemsetAsync(h2acc, 0, sizeof(float) * 64 * 512 + sizeof(int) * N, stream);

    k_init<<<1, 512, 0, stream>>>(g, Wc, wfrag, bcur, NBK);
    k_bscatter<<<HB, NTS, 0, stream>>>(row, col, bcur, degcnt, ebuck, E, NBK, epb);
    k_prep<<<NBK, NT, 0, stream>>>(degcnt, bcur, ebuck, x, dis, rdis,
                                   (__half*)xh, (__half*)xsh, offs, entries, N);
    k_prop1<<<((size_t)N * 8 + NT - 1) / NT, NT, 0, stream>>>(offs, entries, dis, (const __half*)xsh, (__half*)xs2h, N);
    k_combine_f<<<(N + 63) / 64, NT, 0, stream>>>(offs, entries, dis, rdis, (const __half*)xs2h, xh, wfrag, bc, batch, g, N);
    k_mlp12<<<512, NT, 0, stream>>>(g, W1, b1, W2, h2acc);
    k_mlp3p<<<64, NT, 0, stream>>>(h2acc, b2, W3, b3, out);
}